// Round 1
// baseline (892.953 us; speedup 1.0000x reference)
//
#include <hip/hip_runtime.h>

#define N_TOK 65536
#define D 64
#define C_CODES 2048
#define DECAYF 0.8f
#define OMDF 0.2f
#define EPSF 1e-5f
#define SEG 16       // sorted positions per wave in seg_sum
#define KSLOT 32     // LDS candidate slots per token
#define CAND_MAX 8   // global survivor cap per token
#define MARGIN 0.25f // >> 2*eps_worst (~3e-3) of the split-bf16 screen
#define NTILE (C_CODES / 16)

// output layout (floats), concatenated in reference return order
#define OUT_QUANT 0
#define OUT_IND   (N_TOK * D)               // 4194304
#define OUT_EMB   (OUT_IND + N_TOK)         // 4259840
#define OUT_CS    (OUT_EMB + C_CODES * D)   // 4390912
#define OUT_EAVG  (OUT_CS + C_CODES)        // 4392960

typedef short s16x8 __attribute__((ext_vector_type(8)));  // 8 bf16 (4 VGPRs)
typedef float f32x4 __attribute__((ext_vector_type(4)));

__device__ __forceinline__ unsigned short f2bf(float f) {  // RNE float->bf16 bits
    unsigned int u = __float_as_uint(f);
    return (unsigned short)((u + 0x7fffu + ((u >> 16) & 1u)) >> 16);
}
__device__ __forceinline__ float bf2f(unsigned short h) {
    return __uint_as_float(((unsigned int)h) << 16);
}

__global__ void e2_kernel(const float* __restrict__ emb, float* __restrict__ e2) {
    int c = blockIdx.x * blockDim.x + threadIdx.x;
    const float4* er = (const float4*)(emb + (size_t)c * D);
    float s0 = 0.f, s1 = 0.f, s2 = 0.f, s3 = 0.f;
#pragma unroll
    for (int i = 0; i < D / 4; ++i) {
        float4 e = er[i];
        s0 = fmaf(e.x, e.x, s0);
        s1 = fmaf(e.y, e.y, s1);
        s2 = fmaf(e.z, e.z, s2);
        s3 = fmaf(e.w, e.w, s3);
    }
    e2[c] = (s0 + s1) + (s2 + s3);
}

// hi/lo bf16 split of the codebook. hi = RNE(e); lo = RNE(e - hi). Captures
// >=17 mantissa bits so the screening dot error is <= ~1.5e-3 worst case.
__global__ void eprep_kernel(const float* __restrict__ emb,
                             short* __restrict__ ehi, short* __restrict__ elo) {
    int g = blockIdx.x * blockDim.x + threadIdx.x;  // [0, C_CODES*8)
    const float4* ep = (const float4*)(emb) + (size_t)g * 2;
    float4 a = ep[0], b = ep[1];
    float v[8] = {a.x, a.y, a.z, a.w, b.x, b.y, b.z, b.w};
    s16x8 h, l;
#pragma unroll
    for (int j = 0; j < 8; ++j) {
        unsigned short hb = f2bf(v[j]);
        h[j] = (short)hb;
        l[j] = (short)f2bf(v[j] - bf2f(hb));
    }
    ((s16x8*)ehi)[g] = h;
    ((s16x8*)elo)[g] = l;
}

__device__ __forceinline__ void cand_insert(int t, int code, float score,
                                            int* cnt, int* ccode, float* cscore) {
    int slot = atomicAdd(&cnt[t], 1);
    if (slot < KSLOT) {
        ccode[t * KSLOT + slot] = code;
        cscore[t * KSLOT + slot] = score;
    }
}

// One 16(tokens)x16(codes) score tile: 3 split products x K=64 -> 6 MFMAs.
// score = e2[c] - 2*dot  (x^2 omitted: constant per token, cancels in argmin).
__device__ __forceinline__ void tile_scores(
        const short* __restrict__ ehi, const short* __restrict__ elo,
        const float* __restrict__ e2, int ct, int col, int krow,
        s16x8 ah0, s16x8 ah1, s16x8 al0, s16x8 al1, float* sc) {
    int code = ct * 16 + col;
    const s16x8* eh = (const s16x8*)(ehi + (size_t)code * D + krow * 8);
    const s16x8* el = (const s16x8*)(elo + (size_t)code * D + krow * 8);
    s16x8 bh0 = eh[0], bh1 = eh[4];
    s16x8 bl0 = el[0], bl1 = el[4];
    f32x4 acc = {0.f, 0.f, 0.f, 0.f};
    acc = __builtin_amdgcn_mfma_f32_16x16x32_bf16(ah0, bh0, acc, 0, 0, 0);
    acc = __builtin_amdgcn_mfma_f32_16x16x32_bf16(ah1, bh1, acc, 0, 0, 0);
    acc = __builtin_amdgcn_mfma_f32_16x16x32_bf16(al0, bh0, acc, 0, 0, 0);
    acc = __builtin_amdgcn_mfma_f32_16x16x32_bf16(al1, bh1, acc, 0, 0, 0);
    acc = __builtin_amdgcn_mfma_f32_16x16x32_bf16(ah0, bl0, acc, 0, 0, 0);
    acc = __builtin_amdgcn_mfma_f32_16x16x32_bf16(ah1, bl1, acc, 0, 0, 0);
    float e2c = e2[code];
#pragma unroll
    for (int r = 0; r < 4; ++r) sc[r] = fmaf(-2.0f, acc[r], e2c);
}

// MFMA screening sweep: per wave, 16 tokens x all 2048 codes. Running-min
// threshold (base >= true final min always) provably collects the exact
// argmin and all exact ties; overflow -> flag -> full exact scan fallback.
__global__ __launch_bounds__(256) void screen_kernel(
        const float* __restrict__ x, const short* __restrict__ ehi,
        const short* __restrict__ elo, const float* __restrict__ e2,
        int* __restrict__ gcount, int* __restrict__ gcand) {
    __shared__ int cnt[64];
    __shared__ float finmin[64];
    __shared__ int ccode[64 * KSLOT];
    __shared__ float cscore[64 * KSLOT];
    if (threadIdx.x < 64) cnt[threadIdx.x] = 0;
    __syncthreads();

    const int lane = threadIdx.x & 63;
    const int wave = threadIdx.x >> 6;
    const int col = lane & 15;   // B col / C col (code within tile)
    const int krow = lane >> 4;  // k-group
    const int atok = blockIdx.x * 64 + wave * 16 + col;  // A-row token for loads
    const int tokbase = wave * 16 + krow * 4;            // C-row local token base

    // A fragments: load this token's row as f32, split to bf16 hi/lo in-reg.
    const float4* xp = (const float4*)(x + (size_t)atok * D + krow * 8);
    float4 f0 = xp[0], f1 = xp[1], f2 = xp[8], f3 = xp[9];
    float xv[16] = {f0.x, f0.y, f0.z, f0.w, f1.x, f1.y, f1.z, f1.w,
                    f2.x, f2.y, f2.z, f2.w, f3.x, f3.y, f3.z, f3.w};
    s16x8 ah0, ah1, al0, al1;
#pragma unroll
    for (int j = 0; j < 8; ++j) {
        unsigned short h0 = f2bf(xv[j]);
        ah0[j] = (short)h0;
        al0[j] = (short)f2bf(xv[j] - bf2f(h0));
        unsigned short h1 = f2bf(xv[8 + j]);
        ah1[j] = (short)h1;
        al1[j] = (short)f2bf(xv[8 + j] - bf2f(h1));
    }

    float rmin[4], sc[4];

    // ---- tile 0 bootstrap: full reduce BEFORE inserting (avoids 16 junk) ----
    tile_scores(ehi, elo, e2, 0, col, krow, ah0, ah1, al0, al1, sc);
#pragma unroll
    for (int r = 0; r < 4; ++r) rmin[r] = sc[r];
#pragma unroll
    for (int mk = 1; mk < 16; mk <<= 1)
#pragma unroll
        for (int r = 0; r < 4; ++r)
            rmin[r] = fminf(rmin[r], __shfl_xor(rmin[r], mk, 16));
#pragma unroll
    for (int r = 0; r < 4; ++r)
        if (sc[r] <= rmin[r] + MARGIN)
            cand_insert(tokbase + r, col, sc[r], cnt, ccode, cscore);

    // ---- main sweep: rotating 1-shuffle min mix (lag <= 4 tiles, still a
    // valid upper bound on the final min -> correctness preserved) ----
    for (int ct = 1; ct < NTILE; ++ct) {
        tile_scores(ehi, elo, e2, ct, col, krow, ah0, ah1, al0, al1, sc);
        int code = ct * 16 + col;
#pragma unroll
        for (int r = 0; r < 4; ++r) {
            if (sc[r] <= rmin[r] + MARGIN)
                cand_insert(tokbase + r, code, sc[r], cnt, ccode, cscore);
            rmin[r] = fminf(rmin[r], sc[r]);
        }
        int mk = 1 << (ct & 3);
#pragma unroll
        for (int r = 0; r < 4; ++r)
            rmin[r] = fminf(rmin[r], __shfl_xor(rmin[r], mk, 16));
    }

    // exact per-token screening min
#pragma unroll
    for (int mk = 1; mk < 16; mk <<= 1)
#pragma unroll
        for (int r = 0; r < 4; ++r)
            rmin[r] = fminf(rmin[r], __shfl_xor(rmin[r], mk, 16));
    if (col == 0) {
#pragma unroll
        for (int r = 0; r < 4; ++r) finmin[tokbase + r] = rmin[r];
    }
    __syncthreads();

    // final filter vs true min -> ~1 survivor/token
    if (threadIdx.x < 64) {
        int t = threadIdx.x;
        int gt = blockIdx.x * 64 + t;
        int m = cnt[t];
        int om = 0;
        if (m > KSLOT) {
            om = 255;  // buffer overflow: full exact scan
        } else {
            float thr = finmin[t] + MARGIN;
            for (int i = 0; i < m; ++i) {
                if (cscore[t * KSLOT + i] <= thr) {
                    if (om < CAND_MAX) gcand[gt * CAND_MAX + om] = ccode[t * KSLOT + i];
                    om++;
                }
            }
            if (om > CAND_MAX) om = 255;
        }
        gcount[gt] = om;
    }
}

// Exact rescoring with the VERBATIM validated expression tree + key-min
// (bits<<32|c: ties -> smallest c, matching argmax-first semantics).
// Also merges the old finalize (idx, out_ind, counts).
__global__ void exact_kernel(const float* __restrict__ x, const float* __restrict__ emb,
                             const float* __restrict__ e2,
                             const int* __restrict__ gcount, const int* __restrict__ gcand,
                             int* __restrict__ idx, float* __restrict__ out,
                             float* __restrict__ counts) {
    __shared__ float lcount[C_CODES];
    for (int i = threadIdx.x; i < C_CODES; i += blockDim.x) lcount[i] = 0.0f;
    __syncthreads();
    int n = blockIdx.x * blockDim.x + threadIdx.x;
    const float4* xr = (const float4*)(x + (size_t)n * D);
    float4 xv[D / 4];
#pragma unroll
    for (int i = 0; i < D / 4; ++i) xv[i] = xr[i];
    float s0 = 0.f, s1 = 0.f, s2 = 0.f, s3 = 0.f;
#pragma unroll
    for (int i = 0; i < D / 4; ++i) {
        s0 = fmaf(xv[i].x, xv[i].x, s0);
        s1 = fmaf(xv[i].y, xv[i].y, s1);
        s2 = fmaf(xv[i].z, xv[i].z, s2);
        s3 = fmaf(xv[i].w, xv[i].w, s3);
    }
    float x2 = (s0 + s1) + (s2 + s3);

    unsigned long long best = ~0ull;
    auto eval = [&](int c) {
        const float4* er = (const float4*)(emb + (size_t)c * D);
        float d0 = 0.f, d1 = 0.f, d2 = 0.f, d3 = 0.f;
#pragma unroll
        for (int i = 0; i < D / 4; ++i) {
            float4 e = er[i];
            d0 = fmaf(xv[i].x, e.x, d0);
            d1 = fmaf(xv[i].y, e.y, d1);
            d2 = fmaf(xv[i].z, e.z, d2);
            d3 = fmaf(xv[i].w, e.w, d3);
        }
        float dot = (d0 + d1) + (d2 + d3);
        float dist2 = x2 + e2[c] - 2.0f * dot;
        dist2 = fmaxf(dist2, 0.0f);
        unsigned long long key =
            ((unsigned long long)__float_as_uint(dist2) << 32) | (unsigned int)c;
        best = key < best ? key : best;
    };
    int m = gcount[n];
    if (m >= 1 && m <= CAND_MAX) {
        for (int i = 0; i < m; ++i) eval(gcand[n * CAND_MAX + i]);
    } else {
        for (int c = 0; c < C_CODES; ++c) eval(c);  // flagged fallback
    }
    int c = (int)(best & 0xffffffffull);
    idx[n] = c;
    out[OUT_IND + n] = (float)c;
    atomicAdd(&lcount[c], 1.0f);
    __syncthreads();
    for (int i = threadIdx.x; i < C_CODES; i += blockDim.x) {
        float v = lcount[i];
        if (v != 0.0f) atomicAdd(&counts[i], v);
    }
}

// quantize gather: 16 threads per token, one float4 each.
__global__ void gather_kernel(const float* __restrict__ emb,
                              const int* __restrict__ idx,
                              float* __restrict__ out) {
    int g = blockIdx.x * blockDim.x + threadIdx.x;  // [0, N_TOK*16)
    int n = g >> 4;
    int j = g & 15;
    int c = idx[n];
    float4 e = ((const float4*)emb)[c * (D / 4) + j];
    ((float4*)(out + OUT_QUANT))[g] = e;
}

// Single block: EMA cluster-size + laplace smoothing + exclusive prefix sum.
__global__ void prefix_ema_kernel(const float* __restrict__ counts,
                                  const float* __restrict__ cluster_size,
                                  float* __restrict__ out,
                                  float* __restrict__ smoothed,
                                  int* __restrict__ cursor) {
    __shared__ float scan[256];
    __shared__ float red[256];
    int t = threadIdx.x;
    int base = t * 8;
    float cnt[8], ncs[8];
    float csum = 0.f, nsum = 0.f;
#pragma unroll
    for (int j = 0; j < 8; ++j) {
        cnt[j] = counts[base + j];
        csum += cnt[j];
        ncs[j] = cluster_size[base + j] * DECAYF + cnt[j] * OMDF;
        nsum += ncs[j];
        out[OUT_CS + base + j] = ncs[j];
    }
    scan[t] = csum;
    red[t] = nsum;
    __syncthreads();
    for (int s = 1; s < 256; s <<= 1) {
        float v = scan[t];
        float w = (t >= s) ? scan[t - s] : 0.f;
        __syncthreads();
        scan[t] = v + w;
        __syncthreads();
    }
    for (int s = 128; s > 0; s >>= 1) {
        if (t < s) red[t] += red[t + s];
        __syncthreads();
    }
    float tot = red[0];
    float run = (t == 0) ? 0.f : scan[t - 1];
#pragma unroll
    for (int j = 0; j < 8; ++j) {
        cursor[base + j] = (int)run;  // counts are small ints in float: exact
        run += cnt[j];
        smoothed[base + j] = (ncs[j] + EPSF) / (tot + (float)C_CODES * EPSF) * tot;
    }
}

// counting-sort position scatter; entry packs (code<<16 | token).
__global__ void scatter_pos_kernel(const int* __restrict__ idx,
                                   int* __restrict__ cursor,
                                   unsigned int* __restrict__ sorted) {
    int n = blockIdx.x * blockDim.x + threadIdx.x;
    int c = idx[n];
    int pos = atomicAdd(&cursor[c], 1);
    sorted[pos] = ((unsigned int)c << 16) | (unsigned int)n;
}

// Segmented sum over sorted positions: one 64-lane atomicAdd per run boundary.
__global__ __launch_bounds__(256) void seg_sum_kernel(
        const float* __restrict__ x, const unsigned int* __restrict__ sorted,
        float* __restrict__ embed_sum) {
    int lane = threadIdx.x & 63;
    int q = blockIdx.x * 4 + (threadIdx.x >> 6);  // wave id
    int p0 = q * SEG;

    unsigned int mine = (lane < SEG) ? sorted[p0 + lane] : 0u;
    unsigned int pk[SEG];
#pragma unroll
    for (int j = 0; j < SEG; ++j) pk[j] = __shfl(mine, j, 64);

    float xv[SEG];
#pragma unroll
    for (int j = 0; j < SEG; ++j)
        xv[j] = x[(size_t)(pk[j] & 0xffffu) * D + lane];

    unsigned int run_c = 0xffffffffu;
    float sum = 0.f;
#pragma unroll
    for (int j = 0; j < SEG; ++j) {
        unsigned int c = pk[j] >> 16;  // wave-uniform
        if (c != run_c) {
            if (run_c != 0xffffffffu)
                atomicAdd(&embed_sum[(size_t)run_c * D + lane], sum);
            run_c = c;
            sum = 0.f;
        }
        sum += xv[j];
    }
    atomicAdd(&embed_sum[(size_t)run_c * D + lane], sum);
}

__global__ void ema_embed_kernel(const float* __restrict__ embed_avg,
                                 const float* __restrict__ embed_sum,
                                 const float* __restrict__ smoothed,
                                 float* __restrict__ out) {
    int g = blockIdx.x * blockDim.x + threadIdx.x;  // [0, C_CODES*16)
    int c = g >> 4;
    float4 ea = ((const float4*)embed_avg)[g];
    float4 es = ((const float4*)embed_sum)[g];
    float4 na;
    na.x = ea.x * DECAYF + es.x * OMDF;
    na.y = ea.y * DECAYF + es.y * OMDF;
    na.z = ea.z * DECAYF + es.z * OMDF;
    na.w = ea.w * DECAYF + es.w * OMDF;
    ((float4*)(out + OUT_EAVG))[g] = na;
    float sm = smoothed[c];
    float4 ne;
    ne.x = na.x / sm;
    ne.y = na.y / sm;
    ne.z = na.z / sm;
    ne.w = na.w / sm;
    ((float4*)(out + OUT_EMB))[g] = ne;
}

extern "C" void kernel_launch(void* const* d_in, const int* in_sizes, int n_in,
                              void* d_out, int out_size, void* d_ws, size_t ws_size,
                              hipStream_t stream) {
    const float* x            = (const float*)d_in[0];  // (16,4096,64)
    const float* emb          = (const float*)d_in[1];  // (1,2048,64)
    const float* cluster_size = (const float*)d_in[2];  // (1,2048)
    const float* embed_avg    = (const float*)d_in[3];  // (1,2048,64)
    float* out = (float*)d_out;

    // workspace layout (~3.9 MB, all 16B-aligned)
    float* e2        = (float*)d_ws;                        // 2048
    float* counts    = e2 + C_CODES;                        // 2048 (zeroed)
    float* smoothed  = counts + C_CODES;                    // 2048
    int*   cursor    = (int*)(smoothed + C_CODES);          // 2048
    int*   idx       = cursor + C_CODES;                    // 65536
    unsigned int* sorted = (unsigned int*)(idx + N_TOK);    // 65536
    int*   gcount    = (int*)(sorted + N_TOK);              // 65536
    int*   gcand     = gcount + N_TOK;                      // 65536*8
    float* embed_sum = (float*)(gcand + (size_t)N_TOK * CAND_MAX); // 131072 (zeroed)
    short* ehi       = (short*)(embed_sum + C_CODES * D);   // 131072 bf16 bits
    short* elo       = ehi + C_CODES * D;                   // 131072 bf16 bits

    hipMemsetAsync(counts, 0, C_CODES * sizeof(float), stream);
    hipMemsetAsync(embed_sum, 0, (size_t)C_CODES * D * sizeof(float), stream);

    e2_kernel<<<C_CODES / 256, 256, 0, stream>>>(emb, e2);
    eprep_kernel<<<(C_CODES * 8) / 256, 256, 0, stream>>>(emb, ehi, elo);
    screen_kernel<<<N_TOK / 64, 256, 0, stream>>>(x, ehi, elo, e2, gcount, gcand);
    exact_kernel<<<N_TOK / 256, 256, 0, stream>>>(x, emb, e2, gcount, gcand, idx, out, counts);
    gather_kernel<<<(N_TOK * 16) / 256, 256, 0, stream>>>(emb, idx, out);
    prefix_ema_kernel<<<1, 256, 0, stream>>>(counts, cluster_size, out, smoothed, cursor);
    scatter_pos_kernel<<<N_TOK / 256, 256, 0, stream>>>(idx, cursor, sorted);
    seg_sum_kernel<<<(N_TOK / SEG) / 4, 256, 0, stream>>>(x, sorted, embed_sum);
    ema_embed_kernel<<<(C_CODES * 16) / 256, 256, 0, stream>>>(embed_avg, embed_sum,
                                                              smoothed, out);
}

// Round 2
// 359.556 us; speedup vs baseline: 2.4835x; 2.4835x over previous
//
#include <hip/hip_runtime.h>

#define N_TOK 65536
#define D 64
#define C_CODES 2048
#define DECAYF 0.8f
#define OMDF 0.2f
#define EPSF 1e-5f
#define SEG 16        // sorted positions per wave in seg_sum
#define KSLOT 48      // LDS candidate slots per token
#define CAND_MAX 8    // global survivor cap per token
#define MARGIN 0.125f // >= 4.5x the worst-case split-bf16 screen error (~0.028)
#define NTILE (C_CODES / 16)

// output layout (floats), concatenated in reference return order
#define OUT_QUANT 0
#define OUT_IND   (N_TOK * D)               // 4194304
#define OUT_EMB   (OUT_IND + N_TOK)         // 4259840
#define OUT_CS    (OUT_EMB + C_CODES * D)   // 4390912
#define OUT_EAVG  (OUT_CS + C_CODES)        // 4392960

typedef short s16x8 __attribute__((ext_vector_type(8)));  // 8 bf16 (4 VGPRs)
typedef float f32x4 __attribute__((ext_vector_type(4)));

__device__ __forceinline__ unsigned short f2bf(float f) {  // RNE float->bf16 bits
    unsigned int u = __float_as_uint(f);
    return (unsigned short)((u + 0x7fffu + ((u >> 16) & 1u)) >> 16);
}
__device__ __forceinline__ float bf2f(unsigned short h) {
    return __uint_as_float(((unsigned int)h) << 16);
}
__device__ __forceinline__ unsigned long long shflx64(unsigned long long v, int mask) {
    unsigned int lo = (unsigned int)v, hi = (unsigned int)(v >> 32);
    lo = __shfl_xor(lo, mask, 64);
    hi = __shfl_xor(hi, mask, 64);
    return ((unsigned long long)hi << 32) | lo;
}

__global__ void e2_kernel(const float* __restrict__ emb, float* __restrict__ e2) {
    int c = blockIdx.x * blockDim.x + threadIdx.x;
    const float4* er = (const float4*)(emb + (size_t)c * D);
    float s0 = 0.f, s1 = 0.f, s2 = 0.f, s3 = 0.f;
#pragma unroll
    for (int i = 0; i < D / 4; ++i) {
        float4 e = er[i];
        s0 = fmaf(e.x, e.x, s0);
        s1 = fmaf(e.y, e.y, s1);
        s2 = fmaf(e.z, e.z, s2);
        s3 = fmaf(e.w, e.w, s3);
    }
    e2[c] = (s0 + s1) + (s2 + s3);
}

// hi/lo bf16 split of the codebook. hi = RNE(e); lo = RNE(e - hi).
__global__ void eprep_kernel(const float* __restrict__ emb,
                             short* __restrict__ ehi, short* __restrict__ elo) {
    int g = blockIdx.x * blockDim.x + threadIdx.x;  // [0, C_CODES*8)
    const float4* ep = (const float4*)(emb) + (size_t)g * 2;
    float4 a = ep[0], b = ep[1];
    float v[8] = {a.x, a.y, a.z, a.w, b.x, b.y, b.z, b.w};
    s16x8 h, l;
#pragma unroll
    for (int j = 0; j < 8; ++j) {
        unsigned short hb = f2bf(v[j]);
        h[j] = (short)hb;
        l[j] = (short)f2bf(v[j] - bf2f(hb));
    }
    ((s16x8*)ehi)[g] = h;
    ((s16x8*)elo)[g] = l;
}

__device__ __forceinline__ void cand_insert(int t, int code, float score,
                                            int* cnt, int* ccode, float* cscore) {
    int slot = atomicAdd(&cnt[t], 1);
    if (slot < KSLOT) {
        ccode[t * KSLOT + slot] = code;
        cscore[t * KSLOT + slot] = score;
    }
}

// MFMA screening sweep: per wave, 16 tokens x all 2048 codes. Running-min
// threshold (always >= true final min) provably collects the exact argmin and
// all exact ties; overflow -> flag -> wave-cooperative exact scan in exact_kernel.
__global__ __launch_bounds__(256) void screen_kernel(
        const float* __restrict__ x, const short* __restrict__ ehi,
        const short* __restrict__ elo, const float* __restrict__ e2,
        int* __restrict__ gcount, int* __restrict__ gcand) {
    __shared__ int cnt[64];
    __shared__ float finmin[64];
    __shared__ int ccode[64 * KSLOT];
    __shared__ float cscore[64 * KSLOT];
    if (threadIdx.x < 64) cnt[threadIdx.x] = 0;
    __syncthreads();

    const int lane = threadIdx.x & 63;
    const int wave = threadIdx.x >> 6;
    const int col = lane & 15;   // B col / C col (code within tile)
    const int krow = lane >> 4;  // k-group
    const int atok = blockIdx.x * 64 + wave * 16 + col;  // A-row token for loads
    const int tokbase = wave * 16 + krow * 4;            // C-row local token base

    // A fragments: load this token's row as f32, split to bf16 hi/lo in-reg.
    const float4* xp = (const float4*)(x + (size_t)atok * D + krow * 8);
    float4 f0 = xp[0], f1 = xp[1], f2 = xp[8], f3 = xp[9];
    float xv[16] = {f0.x, f0.y, f0.z, f0.w, f1.x, f1.y, f1.z, f1.w,
                    f2.x, f2.y, f2.z, f2.w, f3.x, f3.y, f3.z, f3.w};
    s16x8 ah0, ah1, al0, al1;
#pragma unroll
    for (int j = 0; j < 8; ++j) {
        unsigned short h0 = f2bf(xv[j]);
        ah0[j] = (short)h0;
        al0[j] = (short)f2bf(xv[j] - bf2f(h0));
        unsigned short h1 = f2bf(xv[8 + j]);
        ah1[j] = (short)h1;
        al1[j] = (short)f2bf(xv[8 + j] - bf2f(h1));
    }

    // 3 independent accumulators: MFMA chains of 2 instead of 6.
    auto compute = [&](int ct_, s16x8 h0, s16x8 h1, s16x8 l0, s16x8 l1, float* sc_) {
        f32x4 a0 = {0.f, 0.f, 0.f, 0.f};
        f32x4 a1 = {0.f, 0.f, 0.f, 0.f};
        f32x4 a2 = {0.f, 0.f, 0.f, 0.f};
        a0 = __builtin_amdgcn_mfma_f32_16x16x32_bf16(ah0, h0, a0, 0, 0, 0);
        a1 = __builtin_amdgcn_mfma_f32_16x16x32_bf16(al0, h0, a1, 0, 0, 0);
        a2 = __builtin_amdgcn_mfma_f32_16x16x32_bf16(ah0, l0, a2, 0, 0, 0);
        a0 = __builtin_amdgcn_mfma_f32_16x16x32_bf16(ah1, h1, a0, 0, 0, 0);
        a1 = __builtin_amdgcn_mfma_f32_16x16x32_bf16(al1, h1, a1, 0, 0, 0);
        a2 = __builtin_amdgcn_mfma_f32_16x16x32_bf16(ah1, l1, a2, 0, 0, 0);
        float e2c = e2[ct_ * 16 + col];
#pragma unroll
        for (int r = 0; r < 4; ++r)
            sc_[r] = fmaf(-2.0f, (a0[r] + a1[r]) + a2[r], e2c);
    };

    float rmin[4], sc[4];

    // tile 0 regs + tile 1 prefetch
    s16x8 ch0, ch1, cl0, cl1, nh0, nh1, nl0, nl1;
    {
        const s16x8* eh = (const s16x8*)(ehi + (size_t)col * D + krow * 8);
        const s16x8* el = (const s16x8*)(elo + (size_t)col * D + krow * 8);
        ch0 = eh[0]; ch1 = eh[4]; cl0 = el[0]; cl1 = el[4];
    }
    {
        int code = 16 + col;
        const s16x8* eh = (const s16x8*)(ehi + (size_t)code * D + krow * 8);
        const s16x8* el = (const s16x8*)(elo + (size_t)code * D + krow * 8);
        nh0 = eh[0]; nh1 = eh[4]; nl0 = el[0]; nl1 = el[4];
    }

    // ---- tile 0 bootstrap: full reduce BEFORE inserting ----
    compute(0, ch0, ch1, cl0, cl1, sc);
#pragma unroll
    for (int r = 0; r < 4; ++r) rmin[r] = sc[r];
#pragma unroll
    for (int mk = 1; mk < 16; mk <<= 1)
#pragma unroll
        for (int r = 0; r < 4; ++r)
            rmin[r] = fminf(rmin[r], __shfl_xor(rmin[r], mk, 16));
#pragma unroll
    for (int r = 0; r < 4; ++r)
        if (sc[r] <= rmin[r] + MARGIN)
            cand_insert(tokbase + r, col, sc[r], cnt, ccode, cscore);

    // ---- main sweep with register prefetch + rotating 1-shuffle min mix ----
    for (int ct = 1; ct < NTILE; ++ct) {
        ch0 = nh0; ch1 = nh1; cl0 = nl0; cl1 = nl1;
        int pcode = (((ct + 1 < NTILE) ? (ct + 1) : ct) << 4) + col;  // branch-free safe addr
        const s16x8* eh = (const s16x8*)(ehi + (size_t)pcode * D + krow * 8);
        const s16x8* el = (const s16x8*)(elo + (size_t)pcode * D + krow * 8);
        nh0 = eh[0]; nh1 = eh[4]; nl0 = el[0]; nl1 = el[4];

        compute(ct, ch0, ch1, cl0, cl1, sc);
        int code = ct * 16 + col;
#pragma unroll
        for (int r = 0; r < 4; ++r) {
            if (sc[r] <= rmin[r] + MARGIN)
                cand_insert(tokbase + r, code, sc[r], cnt, ccode, cscore);
            rmin[r] = fminf(rmin[r], sc[r]);
        }
        int mk = 1 << (ct & 3);
#pragma unroll
        for (int r = 0; r < 4; ++r)
            rmin[r] = fminf(rmin[r], __shfl_xor(rmin[r], mk, 16));
    }

    // exact per-token screening min
#pragma unroll
    for (int mk = 1; mk < 16; mk <<= 1)
#pragma unroll
        for (int r = 0; r < 4; ++r)
            rmin[r] = fminf(rmin[r], __shfl_xor(rmin[r], mk, 16));
    if (col == 0) {
#pragma unroll
        for (int r = 0; r < 4; ++r) finmin[tokbase + r] = rmin[r];
    }
    __syncthreads();

    // final filter vs true min -> ~1 survivor/token
    if (threadIdx.x < 64) {
        int t = threadIdx.x;
        int gt = blockIdx.x * 64 + t;
        int m = cnt[t];
        int om = 0;
        if (m > KSLOT) {
            om = 255;  // buffer overflow: cooperative exact scan
        } else {
            float thr = finmin[t] + MARGIN;
            for (int i = 0; i < m; ++i) {
                if (cscore[t * KSLOT + i] <= thr) {
                    if (om < CAND_MAX) gcand[gt * CAND_MAX + om] = ccode[t * KSLOT + i];
                    om++;
                }
            }
            if (om > CAND_MAX) om = 255;
        }
        gcount[gt] = om;
    }
}

// Exact rescoring with the VERBATIM validated expression tree + key-min
// (bits<<32|c: ties -> smallest c, matching argmax-first semantics).
// Fallback tokens are handled WAVE-COOPERATIVELY (64 lanes x 32 codes,
// packed-key butterfly min): ~1.7us/token instead of ~400us serial.
__global__ __launch_bounds__(256) void exact_kernel(
        const float* __restrict__ x, const float* __restrict__ emb,
        const float* __restrict__ e2,
        const int* __restrict__ gcount, const int* __restrict__ gcand,
        int* __restrict__ idx, float* __restrict__ out,
        float* __restrict__ counts) {
    __shared__ float lcount[C_CODES];
    for (int i = threadIdx.x; i < C_CODES; i += blockDim.x) lcount[i] = 0.0f;
    __syncthreads();
    int n = blockIdx.x * blockDim.x + threadIdx.x;
    int lane = threadIdx.x & 63;

    const float4* xr = (const float4*)(x + (size_t)n * D);
    float4 xv[D / 4];
#pragma unroll
    for (int i = 0; i < D / 4; ++i) xv[i] = xr[i];
    float s0 = 0.f, s1 = 0.f, s2 = 0.f, s3 = 0.f;
#pragma unroll
    for (int i = 0; i < D / 4; ++i) {
        s0 = fmaf(xv[i].x, xv[i].x, s0);
        s1 = fmaf(xv[i].y, xv[i].y, s1);
        s2 = fmaf(xv[i].z, xv[i].z, s2);
        s3 = fmaf(xv[i].w, xv[i].w, s3);
    }
    float x2 = (s0 + s1) + (s2 + s3);

    unsigned long long best = ~0ull;
    int m = gcount[n];
    bool fb = (m < 1 || m > CAND_MAX);
    if (!fb) {
        for (int i = 0; i < m; ++i) {
            int c = gcand[n * CAND_MAX + i];
            const float4* er = (const float4*)(emb + (size_t)c * D);
            float d0 = 0.f, d1 = 0.f, d2 = 0.f, d3 = 0.f;
#pragma unroll
            for (int i2 = 0; i2 < D / 4; ++i2) {
                float4 e = er[i2];
                d0 = fmaf(xv[i2].x, e.x, d0);
                d1 = fmaf(xv[i2].y, e.y, d1);
                d2 = fmaf(xv[i2].z, e.z, d2);
                d3 = fmaf(xv[i2].w, e.w, d3);
            }
            float dot = (d0 + d1) + (d2 + d3);
            float dist2 = x2 + e2[c] - 2.0f * dot;
            dist2 = fmaxf(dist2, 0.0f);
            unsigned long long key =
                ((unsigned long long)__float_as_uint(dist2) << 32) | (unsigned int)c;
            best = key < best ? key : best;
        }
    }

    // cooperative exact scan for flagged lanes of this wave
    unsigned long long bal = __ballot(fb);
    while (bal) {
        int src = (int)__ffsll((long long)bal) - 1;
        bal &= bal - 1;
        int tn = (n & ~63) + src;  // token owned by lane `src` of this wave
        const float4* tr = (const float4*)(x + (size_t)tn * D);
        float4 tv[D / 4];
#pragma unroll
        for (int i = 0; i < D / 4; ++i) tv[i] = tr[i];
        float t0 = 0.f, t1 = 0.f, t2 = 0.f, t3 = 0.f;
#pragma unroll
        for (int i = 0; i < D / 4; ++i) {
            t0 = fmaf(tv[i].x, tv[i].x, t0);
            t1 = fmaf(tv[i].y, tv[i].y, t1);
            t2 = fmaf(tv[i].z, tv[i].z, t2);
            t3 = fmaf(tv[i].w, tv[i].w, t3);
        }
        float tx2 = (t0 + t1) + (t2 + t3);
        unsigned long long kbest = ~0ull;
        for (int c = lane; c < C_CODES; c += 64) {
            const float4* er = (const float4*)(emb + (size_t)c * D);
            float d0 = 0.f, d1 = 0.f, d2 = 0.f, d3 = 0.f;
#pragma unroll
            for (int i = 0; i < D / 4; ++i) {
                float4 e = er[i];
                d0 = fmaf(tv[i].x, e.x, d0);
                d1 = fmaf(tv[i].y, e.y, d1);
                d2 = fmaf(tv[i].z, e.z, d2);
                d3 = fmaf(tv[i].w, e.w, d3);
            }
            float dot = (d0 + d1) + (d2 + d3);
            float dist2 = tx2 + e2[c] - 2.0f * dot;
            dist2 = fmaxf(dist2, 0.0f);
            unsigned long long key =
                ((unsigned long long)__float_as_uint(dist2) << 32) | (unsigned int)c;
            kbest = key < kbest ? key : kbest;
        }
#pragma unroll
        for (int mk = 1; mk < 64; mk <<= 1) {
            unsigned long long o = shflx64(kbest, mk);
            kbest = o < kbest ? o : kbest;
        }
        if (lane == src) best = kbest;
    }

    int c = (int)(best & 0xffffffffull);
    idx[n] = c;
    out[OUT_IND + n] = (float)c;
    atomicAdd(&lcount[c], 1.0f);
    __syncthreads();
    for (int i = threadIdx.x; i < C_CODES; i += blockDim.x) {
        float v = lcount[i];
        if (v != 0.0f) atomicAdd(&counts[i], v);
    }
}

// quantize gather: 16 threads per token, one float4 each.
__global__ void gather_kernel(const float* __restrict__ emb,
                              const int* __restrict__ idx,
                              float* __restrict__ out) {
    int g = blockIdx.x * blockDim.x + threadIdx.x;  // [0, N_TOK*16)
    int n = g >> 4;
    int j = g & 15;
    int c = idx[n];
    float4 e = ((const float4*)emb)[c * (D / 4) + j];
    ((float4*)(out + OUT_QUANT))[g] = e;
}

// Single block: EMA cluster-size + laplace smoothing + exclusive prefix sum.
__global__ void prefix_ema_kernel(const float* __restrict__ counts,
                                  const float* __restrict__ cluster_size,
                                  float* __restrict__ out,
                                  float* __restrict__ smoothed,
                                  int* __restrict__ cursor) {
    __shared__ float scan[256];
    __shared__ float red[256];
    int t = threadIdx.x;
    int base = t * 8;
    float cnt[8], ncs[8];
    float csum = 0.f, nsum = 0.f;
#pragma unroll
    for (int j = 0; j < 8; ++j) {
        cnt[j] = counts[base + j];
        csum += cnt[j];
        ncs[j] = cluster_size[base + j] * DECAYF + cnt[j] * OMDF;
        nsum += ncs[j];
        out[OUT_CS + base + j] = ncs[j];
    }
    scan[t] = csum;
    red[t] = nsum;
    __syncthreads();
    for (int s = 1; s < 256; s <<= 1) {
        float v = scan[t];
        float w = (t >= s) ? scan[t - s] : 0.f;
        __syncthreads();
        scan[t] = v + w;
        __syncthreads();
    }
    for (int s = 128; s > 0; s >>= 1) {
        if (t < s) red[t] += red[t + s];
        __syncthreads();
    }
    float tot = red[0];
    float run = (t == 0) ? 0.f : scan[t - 1];
#pragma unroll
    for (int j = 0; j < 8; ++j) {
        cursor[base + j] = (int)run;  // counts are small ints in float: exact
        run += cnt[j];
        smoothed[base + j] = (ncs[j] + EPSF) / (tot + (float)C_CODES * EPSF) * tot;
    }
}

// counting-sort position scatter; entry packs (code<<16 | token).
__global__ void scatter_pos_kernel(const int* __restrict__ idx,
                                   int* __restrict__ cursor,
                                   unsigned int* __restrict__ sorted) {
    int n = blockIdx.x * blockDim.x + threadIdx.x;
    int c = idx[n];
    int pos = atomicAdd(&cursor[c], 1);
    sorted[pos] = ((unsigned int)c << 16) | (unsigned int)n;
}

// Segmented sum over sorted positions: one 64-lane atomicAdd per run boundary.
__global__ __launch_bounds__(256) void seg_sum_kernel(
        const float* __restrict__ x, const unsigned int* __restrict__ sorted,
        float* __restrict__ embed_sum) {
    int lane = threadIdx.x & 63;
    int q = blockIdx.x * 4 + (threadIdx.x >> 6);  // wave id
    int p0 = q * SEG;

    unsigned int mine = (lane < SEG) ? sorted[p0 + lane] : 0u;
    unsigned int pk[SEG];
#pragma unroll
    for (int j = 0; j < SEG; ++j) pk[j] = __shfl(mine, j, 64);

    float xv[SEG];
#pragma unroll
    for (int j = 0; j < SEG; ++j)
        xv[j] = x[(size_t)(pk[j] & 0xffffu) * D + lane];

    unsigned int run_c = 0xffffffffu;
    float sum = 0.f;
#pragma unroll
    for (int j = 0; j < SEG; ++j) {
        unsigned int c = pk[j] >> 16;  // wave-uniform
        if (c != run_c) {
            if (run_c != 0xffffffffu)
                atomicAdd(&embed_sum[(size_t)run_c * D + lane], sum);
            run_c = c;
            sum = 0.f;
        }
        sum += xv[j];
    }
    atomicAdd(&embed_sum[(size_t)run_c * D + lane], sum);
}

__global__ void ema_embed_kernel(const float* __restrict__ embed_avg,
                                 const float* __restrict__ embed_sum,
                                 const float* __restrict__ smoothed,
                                 float* __restrict__ out) {
    int g = blockIdx.x * blockDim.x + threadIdx.x;  // [0, C_CODES*16)
    int c = g >> 4;
    float4 ea = ((const float4*)embed_avg)[g];
    float4 es = ((const float4*)embed_sum)[g];
    float4 na;
    na.x = ea.x * DECAYF + es.x * OMDF;
    na.y = ea.y * DECAYF + es.y * OMDF;
    na.z = ea.z * DECAYF + es.z * OMDF;
    na.w = ea.w * DECAYF + es.w * OMDF;
    ((float4*)(out + OUT_EAVG))[g] = na;
    float sm = smoothed[c];
    float4 ne;
    ne.x = na.x / sm;
    ne.y = na.y / sm;
    ne.z = na.z / sm;
    ne.w = na.w / sm;
    ((float4*)(out + OUT_EMB))[g] = ne;
}

extern "C" void kernel_launch(void* const* d_in, const int* in_sizes, int n_in,
                              void* d_out, int out_size, void* d_ws, size_t ws_size,
                              hipStream_t stream) {
    const float* x            = (const float*)d_in[0];  // (16,4096,64)
    const float* emb          = (const float*)d_in[1];  // (1,2048,64)
    const float* cluster_size = (const float*)d_in[2];  // (1,2048)
    const float* embed_avg    = (const float*)d_in[3];  // (1,2048,64)
    float* out = (float*)d_out;

    // workspace layout (~3.9 MB, all 16B-aligned)
    float* e2        = (float*)d_ws;                        // 2048
    float* counts    = e2 + C_CODES;                        // 2048 (zeroed)
    float* smoothed  = counts + C_CODES;                    // 2048
    int*   cursor    = (int*)(smoothed + C_CODES);          // 2048
    int*   idx       = cursor + C_CODES;                    // 65536
    unsigned int* sorted = (unsigned int*)(idx + N_TOK);    // 65536
    int*   gcount    = (int*)(sorted + N_TOK);              // 65536
    int*   gcand     = gcount + N_TOK;                      // 65536*8
    float* embed_sum = (float*)(gcand + (size_t)N_TOK * CAND_MAX); // 131072 (zeroed)
    short* ehi       = (short*)(embed_sum + C_CODES * D);   // 131072 bf16 bits
    short* elo       = ehi + C_CODES * D;                   // 131072 bf16 bits

    hipMemsetAsync(counts, 0, C_CODES * sizeof(float), stream);
    hipMemsetAsync(embed_sum, 0, (size_t)C_CODES * D * sizeof(float), stream);

    e2_kernel<<<C_CODES / 256, 256, 0, stream>>>(emb, e2);
    eprep_kernel<<<(C_CODES * 8) / 256, 256, 0, stream>>>(emb, ehi, elo);
    screen_kernel<<<N_TOK / 64, 256, 0, stream>>>(x, ehi, elo, e2, gcount, gcand);
    exact_kernel<<<N_TOK / 256, 256, 0, stream>>>(x, emb, e2, gcount, gcand, idx, out, counts);
    gather_kernel<<<(N_TOK * 16) / 256, 256, 0, stream>>>(emb, idx, out);
    prefix_ema_kernel<<<1, 256, 0, stream>>>(counts, cluster_size, out, smoothed, cursor);
    scatter_pos_kernel<<<N_TOK / 256, 256, 0, stream>>>(idx, cursor, sorted);
    seg_sum_kernel<<<(N_TOK / SEG) / 4, 256, 0, stream>>>(x, sorted, embed_sum);
    ema_embed_kernel<<<(C_CODES * 16) / 256, 256, 0, stream>>>(embed_avg, embed_sum,
                                                              smoothed, out);
}

// Round 3
// 278.463 us; speedup vs baseline: 3.2067x; 1.2912x over previous
//
#include <hip/hip_runtime.h>

#define N_TOK 65536
#define D 64
#define C_CODES 2048
#define DECAYF 0.8f
#define OMDF 0.2f
#define EPSF 1e-5f
#define SEG 16        // sorted positions per wave in seg_sum
#define KSLOT 30      // LDS candidate slots per token
#define CAND_MAX 8    // global survivor cap per token
#define MARGIN 0.125f // >= 4.5x the worst-case split-bf16 screen error
#define TCODES 32     // codes per staged LDS tile
#define NT (C_CODES / TCODES)  // 64 tiles
#define NSUB (C_CODES / 16)    // 128 16-code subtiles

// output layout (floats), concatenated in reference return order
#define OUT_QUANT 0
#define OUT_IND   (N_TOK * D)               // 4194304
#define OUT_EMB   (OUT_IND + N_TOK)         // 4259840
#define OUT_CS    (OUT_EMB + C_CODES * D)   // 4390912
#define OUT_EAVG  (OUT_CS + C_CODES)        // 4392960

typedef short s16x8 __attribute__((ext_vector_type(8)));  // 8 bf16 (4 VGPRs)
typedef float f32x4 __attribute__((ext_vector_type(4)));

__device__ __forceinline__ unsigned short f2bf(float f) {  // RNE float->bf16 bits
    unsigned int u = __float_as_uint(f);
    return (unsigned short)((u + 0x7fffu + ((u >> 16) & 1u)) >> 16);
}
__device__ __forceinline__ float bf2f(unsigned short h) {
    return __uint_as_float(((unsigned int)h) << 16);
}
__device__ __forceinline__ unsigned long long shflx64(unsigned long long v, int mask) {
    unsigned int lo = (unsigned int)v, hi = (unsigned int)(v >> 32);
    lo = __shfl_xor(lo, mask, 64);
    hi = __shfl_xor(hi, mask, 64);
    return ((unsigned long long)hi << 32) | lo;
}
__device__ __forceinline__ void gload_lds16(const void* g, void* l) {
    __builtin_amdgcn_global_load_lds(
        (const __attribute__((address_space(1))) void*)g,
        (__attribute__((address_space(3))) void*)l, 16, 0, 0);
}

__global__ void e2_kernel(const float* __restrict__ emb, float* __restrict__ e2) {
    int c = blockIdx.x * blockDim.x + threadIdx.x;
    const float4* er = (const float4*)(emb + (size_t)c * D);
    float s0 = 0.f, s1 = 0.f, s2 = 0.f, s3 = 0.f;
#pragma unroll
    for (int i = 0; i < D / 4; ++i) {
        float4 e = er[i];
        s0 = fmaf(e.x, e.x, s0);
        s1 = fmaf(e.y, e.y, s1);
        s2 = fmaf(e.z, e.z, s2);
        s3 = fmaf(e.w, e.w, s3);
    }
    e2[c] = (s0 + s1) + (s2 + s3);
}

// hi/lo bf16 split of the codebook, stored PRE-SWIZZLED for conflict-free LDS:
// ebk row (256B/code) = [hi slots 0..7][lo slots 0..7], 16B slots, where
// slot s holds source k-chunk (s ^ (code&7)). Linear global_load_lds staging
// then yields an LDS tile readable conflict-free by ds_read_b128.
// Also zeroes counts and embed_sum (replaces two hipMemsetAsync dispatches).
__global__ void eprep_kernel(const float* __restrict__ emb, short* __restrict__ ebk,
                             float* __restrict__ counts, float* __restrict__ embed_sum) {
    int g = blockIdx.x * blockDim.x + threadIdx.x;  // [0, C_CODES*8)
    int code = g >> 3, slot = g & 7;
    int kc = slot ^ (code & 7);
    const float4* ep = (const float4*)(emb + (size_t)code * D + kc * 8);
    float4 a = ep[0], b = ep[1];
    float v[8] = {a.x, a.y, a.z, a.w, b.x, b.y, b.z, b.w};
    s16x8 h, l;
#pragma unroll
    for (int j = 0; j < 8; ++j) {
        unsigned short hb = f2bf(v[j]);
        h[j] = (short)hb;
        l[j] = (short)f2bf(v[j] - bf2f(hb));
    }
    *(s16x8*)(ebk + (size_t)code * 128 + slot * 8) = h;
    *(s16x8*)(ebk + (size_t)code * 128 + 64 + slot * 8) = l;

    float4 z = {0.f, 0.f, 0.f, 0.f};
    ((float4*)embed_sum)[g * 2] = z;      // 16384 threads x 2 = 32768 float4
    ((float4*)embed_sum)[g * 2 + 1] = z;  //   = 131072 floats
    if (g < C_CODES / 4) ((float4*)counts)[g] = z;
}

__device__ __forceinline__ void cand_insert(int t, int code, float score,
                                            int* cnt, int* ccode, float* cscore) {
    int slot = atomicAdd(&cnt[t], 1);
    if (slot < KSLOT) {
        ccode[t * KSLOT + slot] = code;
        cscore[t * KSLOT + slot] = score;
    }
}

// MFMA screening sweep, LDS-staged: per block, 64 tokens x all 2048 codes.
// Codebook tiles stream through double-buffered LDS via global_load_lds;
// e2 staged once. Scoring numerics identical to the validated round-2 path.
__global__ __launch_bounds__(256) void screen_kernel(
        const float* __restrict__ x, const short* __restrict__ ebk,
        const float* __restrict__ e2, int* __restrict__ gcount,
        int* __restrict__ gcand) {
    __shared__ float e2s[C_CODES];                      // 8192 B
    __shared__ __align__(16) char bstage[2][TCODES * 256];  // 2 x 8192 B
    __shared__ int cnt[64];
    __shared__ float finmin[64];
    __shared__ int ccode[64 * KSLOT];
    __shared__ float cscore[64 * KSLOT];

    const int tid = threadIdx.x;
    ((float4*)e2s)[tid] = ((const float4*)e2)[tid];
    ((float4*)e2s)[tid + 256] = ((const float4*)e2)[tid + 256];
    if (tid < 64) cnt[tid] = 0;

    const int lane = tid & 63;
    const int wave = tid >> 6;
    const int col = lane & 15;   // B col / C col (code within subtile)
    const int krow = lane >> 4;  // k-group
    const int atok = blockIdx.x * 64 + wave * 16 + col;  // A-row token for loads
    const int tokbase = wave * 16 + krow * 4;            // C-row local token base

    // A fragments: load this token's row as f32, split to bf16 hi/lo in-reg.
    const float4* xp = (const float4*)(x + (size_t)atok * D + krow * 8);
    float4 f0 = xp[0], f1 = xp[1], f2 = xp[8], f3 = xp[9];
    float xv[16] = {f0.x, f0.y, f0.z, f0.w, f1.x, f1.y, f1.z, f1.w,
                    f2.x, f2.y, f2.z, f2.w, f3.x, f3.y, f3.z, f3.w};
    s16x8 ah0, ah1, al0, al1;
#pragma unroll
    for (int j = 0; j < 8; ++j) {
        unsigned short h0 = f2bf(xv[j]);
        ah0[j] = (short)h0;
        al0[j] = (short)f2bf(xv[j] - bf2f(h0));
        unsigned short h1 = f2bf(xv[8 + j]);
        ah1[j] = (short)h1;
        al1[j] = (short)f2bf(xv[8 + j] - bf2f(h1));
    }

    // stage one 32-code tile (8 KB): 4 waves x 2 x global_load_lds(16B)
    auto stage = [&](int b, int t) {
        const char* src = (const char*)ebk + (size_t)t * (TCODES * 256)
                          + wave * 2048 + lane * 16;
        char* dst = &bstage[b][wave * 2048];
        gload_lds16(src, dst);
        gload_lds16(src + 1024, dst + 1024);
    };

    // one 16-code subtile: 4 ds_read_b128 (swizzled) + 6 MFMA + epilogue
    auto subtile = [&](const char* lb, int st, float* sc_) {
        const char* base = lb + ((st & 1) << 12) + (col << 8);
        int off = (krow ^ (col & 7)) << 4;
        s16x8 bh0 = *(const s16x8*)(base + off);
        s16x8 bh1 = *(const s16x8*)(base + (off ^ 64));
        s16x8 bl0 = *(const s16x8*)(base + 128 + off);
        s16x8 bl1 = *(const s16x8*)(base + 128 + (off ^ 64));
        f32x4 a0 = {0.f, 0.f, 0.f, 0.f};
        f32x4 a1 = {0.f, 0.f, 0.f, 0.f};
        f32x4 a2 = {0.f, 0.f, 0.f, 0.f};
        a0 = __builtin_amdgcn_mfma_f32_16x16x32_bf16(ah0, bh0, a0, 0, 0, 0);
        a1 = __builtin_amdgcn_mfma_f32_16x16x32_bf16(al0, bh0, a1, 0, 0, 0);
        a2 = __builtin_amdgcn_mfma_f32_16x16x32_bf16(ah0, bl0, a2, 0, 0, 0);
        a0 = __builtin_amdgcn_mfma_f32_16x16x32_bf16(ah1, bh1, a0, 0, 0, 0);
        a1 = __builtin_amdgcn_mfma_f32_16x16x32_bf16(al1, bh1, a1, 0, 0, 0);
        a2 = __builtin_amdgcn_mfma_f32_16x16x32_bf16(ah1, bl1, a2, 0, 0, 0);
        float e2c = e2s[st * 16 + col];
#pragma unroll
        for (int r = 0; r < 4; ++r)
            sc_[r] = fmaf(-2.0f, (a0[r] + a1[r]) + a2[r], e2c);
    };

    float rmin[4], sc[4];

    auto normal = [&](int st) {  // insert vs stale rmin, update, rotating mix
        int codeb = st * 16 + col;
#pragma unroll
        for (int r = 0; r < 4; ++r) {
            if (sc[r] <= rmin[r] + MARGIN)
                cand_insert(tokbase + r, codeb, sc[r], cnt, ccode, cscore);
            rmin[r] = fminf(rmin[r], sc[r]);
        }
        int mk = 1 << (st & 3);
#pragma unroll
        for (int r = 0; r < 4; ++r)
            rmin[r] = fminf(rmin[r], __shfl_xor(rmin[r], mk, 16));
    };

    stage(0, 0);
    __syncthreads();  // drains staging + e2s/cnt init

    // ---- tile 0: bootstrap subtile 0 (full reduce BEFORE inserting) ----
    stage(1, 1);
    subtile(bstage[0], 0, sc);
#pragma unroll
    for (int r = 0; r < 4; ++r) rmin[r] = sc[r];
#pragma unroll
    for (int mk = 1; mk < 16; mk <<= 1)
#pragma unroll
        for (int r = 0; r < 4; ++r)
            rmin[r] = fminf(rmin[r], __shfl_xor(rmin[r], mk, 16));
#pragma unroll
    for (int r = 0; r < 4; ++r)
        if (sc[r] <= rmin[r] + MARGIN)
            cand_insert(tokbase + r, col, sc[r], cnt, ccode, cscore);
    subtile(bstage[0], 1, sc);
    normal(1);
    __syncthreads();

    // ---- main double-buffered sweep ----
    for (int t = 1; t < NT; ++t) {
        if (t + 1 < NT) stage((t + 1) & 1, t + 1);
        const char* lb = bstage[t & 1];
        subtile(lb, 2 * t, sc);
        normal(2 * t);
        subtile(lb, 2 * t + 1, sc);
        normal(2 * t + 1);
        __syncthreads();
    }

    // exact per-token screening min
#pragma unroll
    for (int mk = 1; mk < 16; mk <<= 1)
#pragma unroll
        for (int r = 0; r < 4; ++r)
            rmin[r] = fminf(rmin[r], __shfl_xor(rmin[r], mk, 16));
    if (col == 0) {
#pragma unroll
        for (int r = 0; r < 4; ++r) finmin[tokbase + r] = rmin[r];
    }
    __syncthreads();

    // final filter vs true min -> ~1 survivor/token
    if (tid < 64) {
        int t = tid;
        int gt = blockIdx.x * 64 + t;
        int m = cnt[t];
        int om = 0;
        if (m > KSLOT) {
            om = 255;  // buffer overflow: cooperative exact scan
        } else {
            float thr = finmin[t] + MARGIN;
            for (int i = 0; i < m; ++i) {
                if (cscore[t * KSLOT + i] <= thr) {
                    if (om < CAND_MAX) gcand[gt * CAND_MAX + om] = ccode[t * KSLOT + i];
                    om++;
                }
            }
            if (om > CAND_MAX) om = 255;
        }
        gcount[gt] = om;
    }
}

// Exact rescoring with the VERBATIM validated expression tree + key-min
// (bits<<32|c: ties -> smallest c, matching argmax-first semantics).
// Fallback tokens are handled WAVE-COOPERATIVELY (64 lanes x 32 codes,
// packed-key butterfly min).
__global__ __launch_bounds__(256) void exact_kernel(
        const float* __restrict__ x, const float* __restrict__ emb,
        const float* __restrict__ e2,
        const int* __restrict__ gcount, const int* __restrict__ gcand,
        int* __restrict__ idx, float* __restrict__ out,
        float* __restrict__ counts) {
    __shared__ float lcount[C_CODES];
    for (int i = threadIdx.x; i < C_CODES; i += blockDim.x) lcount[i] = 0.0f;
    __syncthreads();
    int n = blockIdx.x * blockDim.x + threadIdx.x;
    int lane = threadIdx.x & 63;

    const float4* xr = (const float4*)(x + (size_t)n * D);
    float4 xv[D / 4];
#pragma unroll
    for (int i = 0; i < D / 4; ++i) xv[i] = xr[i];
    float s0 = 0.f, s1 = 0.f, s2 = 0.f, s3 = 0.f;
#pragma unroll
    for (int i = 0; i < D / 4; ++i) {
        s0 = fmaf(xv[i].x, xv[i].x, s0);
        s1 = fmaf(xv[i].y, xv[i].y, s1);
        s2 = fmaf(xv[i].z, xv[i].z, s2);
        s3 = fmaf(xv[i].w, xv[i].w, s3);
    }
    float x2 = (s0 + s1) + (s2 + s3);

    unsigned long long best = ~0ull;
    int m = gcount[n];
    bool fb = (m < 1 || m > CAND_MAX);
    if (!fb) {
        for (int i = 0; i < m; ++i) {
            int c = gcand[n * CAND_MAX + i];
            const float4* er = (const float4*)(emb + (size_t)c * D);
            float d0 = 0.f, d1 = 0.f, d2 = 0.f, d3 = 0.f;
#pragma unroll
            for (int i2 = 0; i2 < D / 4; ++i2) {
                float4 e = er[i2];
                d0 = fmaf(xv[i2].x, e.x, d0);
                d1 = fmaf(xv[i2].y, e.y, d1);
                d2 = fmaf(xv[i2].z, e.z, d2);
                d3 = fmaf(xv[i2].w, e.w, d3);
            }
            float dot = (d0 + d1) + (d2 + d3);
            float dist2 = x2 + e2[c] - 2.0f * dot;
            dist2 = fmaxf(dist2, 0.0f);
            unsigned long long key =
                ((unsigned long long)__float_as_uint(dist2) << 32) | (unsigned int)c;
            best = key < best ? key : best;
        }
    }

    // cooperative exact scan for flagged lanes of this wave
    unsigned long long bal = __ballot(fb);
    while (bal) {
        int src = (int)__ffsll((long long)bal) - 1;
        bal &= bal - 1;
        int tn = (n & ~63) + src;  // token owned by lane `src` of this wave
        const float4* tr = (const float4*)(x + (size_t)tn * D);
        float4 tv[D / 4];
#pragma unroll
        for (int i = 0; i < D / 4; ++i) tv[i] = tr[i];
        float t0 = 0.f, t1 = 0.f, t2 = 0.f, t3 = 0.f;
#pragma unroll
        for (int i = 0; i < D / 4; ++i) {
            t0 = fmaf(tv[i].x, tv[i].x, t0);
            t1 = fmaf(tv[i].y, tv[i].y, t1);
            t2 = fmaf(tv[i].z, tv[i].z, t2);
            t3 = fmaf(tv[i].w, tv[i].w, t3);
        }
        float tx2 = (t0 + t1) + (t2 + t3);
        unsigned long long kbest = ~0ull;
        for (int c = lane; c < C_CODES; c += 64) {
            const float4* er = (const float4*)(emb + (size_t)c * D);
            float d0 = 0.f, d1 = 0.f, d2 = 0.f, d3 = 0.f;
#pragma unroll
            for (int i = 0; i < D / 4; ++i) {
                float4 e = er[i];
                d0 = fmaf(tv[i].x, e.x, d0);
                d1 = fmaf(tv[i].y, e.y, d1);
                d2 = fmaf(tv[i].z, e.z, d2);
                d3 = fmaf(tv[i].w, e.w, d3);
            }
            float dot = (d0 + d1) + (d2 + d3);
            float dist2 = tx2 + e2[c] - 2.0f * dot;
            dist2 = fmaxf(dist2, 0.0f);
            unsigned long long key =
                ((unsigned long long)__float_as_uint(dist2) << 32) | (unsigned int)c;
            kbest = key < kbest ? key : kbest;
        }
#pragma unroll
        for (int mk = 1; mk < 64; mk <<= 1) {
            unsigned long long o = shflx64(kbest, mk);
            kbest = o < kbest ? o : kbest;
        }
        if (lane == src) best = kbest;
    }

    int c = (int)(best & 0xffffffffull);
    idx[n] = c;
    out[OUT_IND + n] = (float)c;
    atomicAdd(&lcount[c], 1.0f);
    __syncthreads();
    for (int i = threadIdx.x; i < C_CODES; i += blockDim.x) {
        float v = lcount[i];
        if (v != 0.0f) atomicAdd(&counts[i], v);
    }
}

// quantize gather: 16 threads per token, one float4 each.
__global__ void gather_kernel(const float* __restrict__ emb,
                              const int* __restrict__ idx,
                              float* __restrict__ out) {
    int g = blockIdx.x * blockDim.x + threadIdx.x;  // [0, N_TOK*16)
    int n = g >> 4;
    int j = g & 15;
    int c = idx[n];
    float4 e = ((const float4*)emb)[c * (D / 4) + j];
    ((float4*)(out + OUT_QUANT))[g] = e;
}

// Single block: EMA cluster-size + laplace smoothing + exclusive prefix sum.
__global__ void prefix_ema_kernel(const float* __restrict__ counts,
                                  const float* __restrict__ cluster_size,
                                  float* __restrict__ out,
                                  float* __restrict__ smoothed,
                                  int* __restrict__ cursor) {
    __shared__ float scan[256];
    __shared__ float red[256];
    int t = threadIdx.x;
    int base = t * 8;
    float cnt[8], ncs[8];
    float csum = 0.f, nsum = 0.f;
#pragma unroll
    for (int j = 0; j < 8; ++j) {
        cnt[j] = counts[base + j];
        csum += cnt[j];
        ncs[j] = cluster_size[base + j] * DECAYF + cnt[j] * OMDF;
        nsum += ncs[j];
        out[OUT_CS + base + j] = ncs[j];
    }
    scan[t] = csum;
    red[t] = nsum;
    __syncthreads();
    for (int s = 1; s < 256; s <<= 1) {
        float v = scan[t];
        float w = (t >= s) ? scan[t - s] : 0.f;
        __syncthreads();
        scan[t] = v + w;
        __syncthreads();
    }
    for (int s = 128; s > 0; s >>= 1) {
        if (t < s) red[t] += red[t + s];
        __syncthreads();
    }
    float tot = red[0];
    float run = (t == 0) ? 0.f : scan[t - 1];
#pragma unroll
    for (int j = 0; j < 8; ++j) {
        cursor[base + j] = (int)run;  // counts are small ints in float: exact
        run += cnt[j];
        smoothed[base + j] = (ncs[j] + EPSF) / (tot + (float)C_CODES * EPSF) * tot;
    }
}

// counting-sort position scatter; entry packs (code<<16 | token).
__global__ void scatter_pos_kernel(const int* __restrict__ idx,
                                   int* __restrict__ cursor,
                                   unsigned int* __restrict__ sorted) {
    int n = blockIdx.x * blockDim.x + threadIdx.x;
    int c = idx[n];
    int pos = atomicAdd(&cursor[c], 1);
    sorted[pos] = ((unsigned int)c << 16) | (unsigned int)n;
}

// Segmented sum over sorted positions: one 64-lane atomicAdd per run boundary.
__global__ __launch_bounds__(256) void seg_sum_kernel(
        const float* __restrict__ x, const unsigned int* __restrict__ sorted,
        float* __restrict__ embed_sum) {
    int lane = threadIdx.x & 63;
    int q = blockIdx.x * 4 + (threadIdx.x >> 6);  // wave id
    int p0 = q * SEG;

    unsigned int mine = (lane < SEG) ? sorted[p0 + lane] : 0u;
    unsigned int pk[SEG];
#pragma unroll
    for (int j = 0; j < SEG; ++j) pk[j] = __shfl(mine, j, 64);

    float xv[SEG];
#pragma unroll
    for (int j = 0; j < SEG; ++j)
        xv[j] = x[(size_t)(pk[j] & 0xffffu) * D + lane];

    unsigned int run_c = 0xffffffffu;
    float sum = 0.f;
#pragma unroll
    for (int j = 0; j < SEG; ++j) {
        unsigned int c = pk[j] >> 16;  // wave-uniform
        if (c != run_c) {
            if (run_c != 0xffffffffu)
                atomicAdd(&embed_sum[(size_t)run_c * D + lane], sum);
            run_c = c;
            sum = 0.f;
        }
        sum += xv[j];
    }
    atomicAdd(&embed_sum[(size_t)run_c * D + lane], sum);
}

__global__ void ema_embed_kernel(const float* __restrict__ embed_avg,
                                 const float* __restrict__ embed_sum,
                                 const float* __restrict__ smoothed,
                                 float* __restrict__ out) {
    int g = blockIdx.x * blockDim.x + threadIdx.x;  // [0, C_CODES*16)
    int c = g >> 4;
    float4 ea = ((const float4*)embed_avg)[g];
    float4 es = ((const float4*)embed_sum)[g];
    float4 na;
    na.x = ea.x * DECAYF + es.x * OMDF;
    na.y = ea.y * DECAYF + es.y * OMDF;
    na.z = ea.z * DECAYF + es.z * OMDF;
    na.w = ea.w * DECAYF + es.w * OMDF;
    ((float4*)(out + OUT_EAVG))[g] = na;
    float sm = smoothed[c];
    float4 ne;
    ne.x = na.x / sm;
    ne.y = na.y / sm;
    ne.z = na.z / sm;
    ne.w = na.w / sm;
    ((float4*)(out + OUT_EMB))[g] = ne;
}

extern "C" void kernel_launch(void* const* d_in, const int* in_sizes, int n_in,
                              void* d_out, int out_size, void* d_ws, size_t ws_size,
                              hipStream_t stream) {
    const float* x            = (const float*)d_in[0];  // (16,4096,64)
    const float* emb          = (const float*)d_in[1];  // (1,2048,64)
    const float* cluster_size = (const float*)d_in[2];  // (1,2048)
    const float* embed_avg    = (const float*)d_in[3];  // (1,2048,64)
    float* out = (float*)d_out;

    // workspace layout (~4 MB, all 16B-aligned)
    float* e2        = (float*)d_ws;                        // 2048
    float* counts    = e2 + C_CODES;                        // 2048 (zeroed in eprep)
    float* smoothed  = counts + C_CODES;                    // 2048
    int*   cursor    = (int*)(smoothed + C_CODES);          // 2048
    int*   idx       = cursor + C_CODES;                    // 65536
    unsigned int* sorted = (unsigned int*)(idx + N_TOK);    // 65536
    int*   gcount    = (int*)(sorted + N_TOK);              // 65536
    int*   gcand     = gcount + N_TOK;                      // 65536*8
    float* embed_sum = (float*)(gcand + (size_t)N_TOK * CAND_MAX); // 131072 (zeroed in eprep)
    short* ebk       = (short*)(embed_sum + C_CODES * D);   // 262144 shorts (512 KB)

    e2_kernel<<<C_CODES / 256, 256, 0, stream>>>(emb, e2);
    eprep_kernel<<<(C_CODES * 8) / 256, 256, 0, stream>>>(emb, ebk, counts, embed_sum);
    screen_kernel<<<N_TOK / 64, 256, 0, stream>>>(x, ebk, e2, gcount, gcand);
    exact_kernel<<<N_TOK / 256, 256, 0, stream>>>(x, emb, e2, gcount, gcand, idx, out, counts);
    gather_kernel<<<(N_TOK * 16) / 256, 256, 0, stream>>>(emb, idx, out);
    prefix_ema_kernel<<<1, 256, 0, stream>>>(counts, cluster_size, out, smoothed, cursor);
    scatter_pos_kernel<<<N_TOK / 256, 256, 0, stream>>>(idx, cursor, sorted);
    seg_sum_kernel<<<(N_TOK / SEG) / 4, 256, 0, stream>>>(x, sorted, embed_sum);
    ema_embed_kernel<<<(C_CODES * 16) / 256, 256, 0, stream>>>(embed_avg, embed_sum,
                                                              smoothed, out);
}